// Round 11
// baseline (642.252 us; speedup 1.0000x reference)
//
#include <hip/hip_runtime.h>
#include <math.h>

// Problem constants
#define NA   4096
#define NPA  8192
#define NT   4096
#define E_AP 80000
#define E_PA 80000
#define E_TP 160000
#define E_TOT (E_AP + E_TP + E_TP/2)  // placeholder guard (unused)
#undef E_TOT
#define E_TOT (E_AP + E_TP + E_PA)
#define NSLOT (NPA + NPA + NA)     // 20480 global CSR slots: [ap->paper | tp->paper | pa->author]
#define ASPLIT 4                   // attention key-splits
#define SCV_BLOCKS 9216            // scorev block count (36864 rows / 4)
#define SCT_BLOCKS ((E_TOT + 255) / 256)

typedef __attribute__((ext_vector_type(4))) float f32x4;
typedef __attribute__((ext_vector_type(8))) short s16x8;
typedef __attribute__((ext_vector_type(8))) unsigned short u16x8;
typedef unsigned short ushort_t;

__device__ __forceinline__ ushort_t f2bf(float f){
  unsigned u = __float_as_uint(f);
  unsigned r = u + 0x7fffu + ((u >> 16) & 1u);   // RNE
  return (ushort_t)(r >> 16);
}
__device__ __forceinline__ float bf2f(ushort_t u){
  return __uint_as_float(((unsigned)u) << 16);
}

// ---------------------------------------------------------------- bf16 MFMA GEMM (templated)
// Tile 64 x TN x BK32, 4 waves (2x2); TN in {64,128}.
// ACT: 0 none, 1 relu, 3 bf16-C + per-row dot with lng(rows<8192)/lnb into rdOut (TN==128, grid.y==1).
template<int ACT, int TN>
__global__ __launch_bounds__(256) void gemm_mfma_k(
    const void* __restrict__ Ain, const void* __restrict__ A2in, const void* __restrict__ A3in,
    int aBf16,
    const float* __restrict__ B, void* __restrict__ Cout, int cBf16,
    const float* __restrict__ bias,
    const float* __restrict__ addmat, int addCols, int addLd,
    const float* __restrict__ lng, const float* __restrict__ lnb,
    float* __restrict__ rdOut,
    int M, int N, int K, int lda, int ldb, int ldc)
{
  const char* A  = (const char*)Ain;
  const char* A2 = (const char*)A2in;
  const char* A3 = (const char*)A3in;
  char* C = (char*)Cout;

  __shared__ __align__(16) ushort_t As[64][40];
  __shared__ __align__(16) ushort_t Bs[TN][40];
  constexpr int NJ = TN / 32;
  int bm = blockIdx.x * 64, bn = blockIdx.y * TN;
  int tid = threadIdx.x;
  int w = tid >> 6, lane = tid & 63, lg = lane >> 4, lid = lane & 15;
  int wm = (w & 1) * 32, wn = (w >> 1) * (TN / 2);
  f32x4 acc[2][NJ];
#pragma unroll
  for (int i = 0; i < 2; ++i)
#pragma unroll
    for (int j = 0; j < NJ; ++j) acc[i][j] = (f32x4){0.f, 0.f, 0.f, 0.f};

  for (int k0 = 0; k0 < K; k0 += 32) {
    {
      int r = tid >> 2, ks = (tid & 3) * 8;
      int kcol = k0 + ks;
      const char* Ab = A;
      if (A2) { int seg = kcol >> 7; Ab = (seg == 0) ? A : ((seg == 1) ? A2 : A3); kcol &= 127; }
      u16x8 v;
      if (aBf16) {
        v = *(const u16x8*)((const ushort_t*)Ab + (size_t)(bm + r) * lda + kcol);
      } else {
        const float* ap = (const float*)Ab + (size_t)(bm + r) * lda + kcol;
#pragma unroll
        for (int j = 0; j < 8; ++j) {
          int gk = k0 + ks + j;
          float fv = (gk < K) ? ap[j] : 0.f;
          v[j] = f2bf(fv);
        }
      }
      *(u16x8*)&As[r][ks] = v;
    }
    if (TN == 128) {
      int n = tid >> 1, ks = (tid & 1) * 16;
      ushort_t tmp[16];
#pragma unroll
      for (int j = 0; j < 16; ++j) {
        int gk = k0 + ks + j;
        float fv = (gk < K) ? B[(size_t)gk * ldb + bn + n] : 0.f;
        tmp[j] = f2bf(fv);
      }
      u16x8 v0, v1;
#pragma unroll
      for (int j = 0; j < 8; ++j) { v0[j] = tmp[j]; v1[j] = tmp[8 + j]; }
      *(u16x8*)&Bs[n][ks] = v0;
      *(u16x8*)&Bs[n][ks + 8] = v1;
    } else {
      int n = tid >> 2, ks = (tid & 3) * 8;
      u16x8 v;
#pragma unroll
      for (int j = 0; j < 8; ++j) {
        int gk = k0 + ks + j;
        float fv = (gk < K) ? B[(size_t)gk * ldb + bn + n] : 0.f;
        v[j] = f2bf(fv);
      }
      *(u16x8*)&Bs[n][ks] = v;
    }
    __syncthreads();
    s16x8 a_frag[2], b_frag[NJ];
#pragma unroll
    for (int i = 0; i < 2; ++i) a_frag[i] = *(s16x8*)&As[wm + i * 16 + lid][lg * 8];
#pragma unroll
    for (int j = 0; j < NJ; ++j) b_frag[j] = *(s16x8*)&Bs[wn + j * 16 + lid][lg * 8];
#pragma unroll
    for (int i = 0; i < 2; ++i)
#pragma unroll
      for (int j = 0; j < NJ; ++j)
        acc[i][j] = __builtin_amdgcn_mfma_f32_16x16x32_bf16(a_frag[i], b_frag[j], acc[i][j], 0, 0, 0);
    __syncthreads();
  }
  if constexpr (ACT == 3) {
    __shared__ float Ct[64][132];
#pragma unroll
    for (int i = 0; i < 2; ++i) {
#pragma unroll
      for (int j = 0; j < NJ; ++j) {
        int coll = wn + j * 16 + lid;
#pragma unroll
        for (int rr = 0; rr < 4; ++rr) {
          int rowl = wm + i * 16 + lg * 4 + rr;
          Ct[rowl][coll] = acc[i][j][rr];
        }
      }
    }
    __syncthreads();
    int row = tid >> 2, part = tid & 3;
    const float* vsel = (bm + row < 8192) ? lng : lnb;
    float rd = 0.f;
    ushort_t* Cu = (ushort_t*)C;
#pragma unroll
    for (int c2 = 0; c2 < 32; ++c2) {
      int c = part * 32 + c2;
      float f = Ct[row][c];
      rd = fmaf(f, vsel[c], rd);
      Cu[(size_t)(bm + row) * ldc + c] = f2bf(f);
    }
    rd += __shfl_xor(rd, 1);
    rd += __shfl_xor(rd, 2);
    if (part == 0) rdOut[bm + row] = rd;
  } else {
#pragma unroll
    for (int i = 0; i < 2; ++i) {
#pragma unroll
      for (int j = 0; j < NJ; ++j) {
        int c = bn + wn + j * 16 + lid;
#pragma unroll
        for (int rr = 0; rr < 4; ++rr) {
          int r = bm + wm + i * 16 + lg * 4 + rr;
          float v = acc[i][j][rr];
          if (bias)   v += bias[c];
          if (addmat && c < addCols) v += addmat[(size_t)r * addLd + c];
          if (ACT == 1) v = fmaxf(v, 0.f);
          if (cBf16) ((ushort_t*)C)[(size_t)r * ldc + c] = f2bf(v);
          else       ((float*)C)[(size_t)r * ldc + c] = v;
        }
      }
    }
  }
}

// ---------------------------------------------------------------- descriptor multi-GEMM body (TN=64)
struct GDesc {
  const void* A; const void* A2;
  const float* B; void* C;
  const float* bias;
  int aBf16, cBf16, act;
  int M, N, K, lda, ldb, ldc;
  int nz, aOffZ, bOffZ, cOffZ;
  int tileStart;
};
struct GDescArr { GDesc d[4]; int nd; };

__device__ __forceinline__ void multi_gemm_body(const GDescArr& da, int t, char* smem){
  int di = 0;
#pragma unroll
  for (int i = 1; i < 4; ++i) if (i < da.nd && t >= da.d[i].tileStart) di = i;
  const int aBf16 = da.d[di].aBf16, cBf16 = da.d[di].cBf16, act = da.d[di].act;
  const int M = da.d[di].M, N = da.d[di].N, K = da.d[di].K;
  const int lda = da.d[di].lda, ldb = da.d[di].ldb, ldc = da.d[di].ldc;
  int local = t - da.d[di].tileStart;
  int tM = M >> 6;
  int perZ = tM * (N >> 6);
  int z = local / perZ, rem = local - z * perZ;
  int bm = (rem % tM) * 64, bn = (rem / tM) * 64;
  int asz = aBf16 ? 2 : 4;
  const char* A  = (const char*)da.d[di].A  + (size_t)z * da.d[di].aOffZ * asz;
  const char* A2 = da.d[di].A2 ? (const char*)da.d[di].A2 + (size_t)z * da.d[di].aOffZ * asz : nullptr;
  const float* B = da.d[di].B + (size_t)z * da.d[di].bOffZ;
  char* C = (char*)da.d[di].C + (size_t)z * da.d[di].cOffZ * (cBf16 ? 2 : 4);
  const float* bias = da.d[di].bias ? da.d[di].bias + (size_t)z * da.d[di].cOffZ : nullptr;

  ushort_t (*As)[40] = (ushort_t(*)[40])smem;
  ushort_t (*Bs)[40] = (ushort_t(*)[40])(smem + 5120);
  int tid = threadIdx.x;
  int w = tid >> 6, lane = tid & 63, lg = lane >> 4, lid = lane & 15;
  int wm = (w & 1) * 32, wn = (w >> 1) * 32;
  f32x4 acc[2][2];
#pragma unroll
  for (int i = 0; i < 2; ++i)
#pragma unroll
    for (int j = 0; j < 2; ++j) acc[i][j] = (f32x4){0.f, 0.f, 0.f, 0.f};

  for (int k0 = 0; k0 < K; k0 += 32) {
    {
      int r = tid >> 2, ks = (tid & 3) * 8;
      int kcol = k0 + ks;
      const char* Ab = A;
      if (A2) { int seg = kcol >> 7; Ab = seg ? A2 : A; kcol &= 127; }
      u16x8 v;
      if (aBf16) {
        v = *(const u16x8*)((const ushort_t*)Ab + (size_t)(bm + r) * lda + kcol);
      } else {
        const float* ap = (const float*)Ab + (size_t)(bm + r) * lda + kcol;
#pragma unroll
        for (int j = 0; j < 8; ++j) {
          int gk = k0 + ks + j;
          float fv = (gk < K) ? ap[j] : 0.f;
          v[j] = f2bf(fv);
        }
      }
      *(u16x8*)&As[r][ks] = v;
    }
    {
      int n = tid >> 2, ks = (tid & 3) * 8;
      u16x8 v;
#pragma unroll
      for (int j = 0; j < 8; ++j) {
        int gk = k0 + ks + j;
        float fv = (gk < K) ? B[(size_t)gk * ldb + bn + n] : 0.f;
        v[j] = f2bf(fv);
      }
      *(u16x8*)&Bs[n][ks] = v;
    }
    __syncthreads();
    s16x8 a_frag[2], b_frag[2];
#pragma unroll
    for (int i = 0; i < 2; ++i) a_frag[i] = *(s16x8*)&As[wm + i * 16 + lid][lg * 8];
#pragma unroll
    for (int j = 0; j < 2; ++j) b_frag[j] = *(s16x8*)&Bs[wn + j * 16 + lid][lg * 8];
#pragma unroll
    for (int i = 0; i < 2; ++i)
#pragma unroll
      for (int j = 0; j < 2; ++j)
        acc[i][j] = __builtin_amdgcn_mfma_f32_16x16x32_bf16(a_frag[i], b_frag[j], acc[i][j], 0, 0, 0);
    __syncthreads();
  }
#pragma unroll
  for (int i = 0; i < 2; ++i) {
#pragma unroll
    for (int j = 0; j < 2; ++j) {
      int c = bn + wn + j * 16 + lid;
#pragma unroll
      for (int rr = 0; rr < 4; ++rr) {
        int r = bm + wm + i * 16 + lg * 4 + rr;
        float v = acc[i][j][rr];
        if (bias) v += bias[c];
        if (act == 1) v = fmaxf(v, 0.f);
        if (cBf16) ((ushort_t*)C)[(size_t)r * ldc + c] = f2bf(v);
        else       ((float*)C)[(size_t)r * ldc + c] = v;
      }
    }
  }
}

__global__ __launch_bounds__(256) void gemm_multi_k(GDescArr da){
  __shared__ __align__(16) char smem[10240];
  multi_gemm_body(da, blockIdx.x, smem);
}

// ---------------------------------------------------------------- loss body (smem-carved)
__device__ __forceinline__ void loss_body(int lb, char* smem,
    const float* __restrict__ peQ, const float* __restrict__ peK,
    const float* __restrict__ A4, float* __restrict__ lossAcc)
{
  ushort_t (*As)[40] = (ushort_t(*)[40])smem;            // 64x40
  ushort_t (*Bs)[40] = (ushort_t(*)[40])(smem + 5120);   // 128x40
  float (*sig)[128]  = (float(*)[128])(smem + 15360);    // 64x128
  float* red         = (float*)(smem + 48128);           // 256
  int br = (lb & 63) * 64, bc = (lb >> 6) * 128;
  int tid = threadIdx.x;
  int w = tid >> 6, lane = tid & 63, lg = lane >> 4, lid = lane & 15;
  int wm = (w & 1) * 32, wn = (w >> 1) * 64;
  f32x4 acc[2][4];
#pragma unroll
  for (int i = 0; i < 2; ++i)
#pragma unroll
    for (int j = 0; j < 4; ++j) acc[i][j] = (f32x4){0.f, 0.f, 0.f, 0.f};

  for (int k0 = 0; k0 < 128; k0 += 32) {
    {
      int r = tid >> 2, ks = (tid & 3) * 8;
      const float* ap = peQ + (size_t)(br + r) * 256 + k0 + ks;
      u16x8 v;
#pragma unroll
      for (int j = 0; j < 8; ++j) v[j] = f2bf(ap[j]);
      *(u16x8*)&As[r][ks] = v;
    }
    {
      int n = tid >> 1, ks = (tid & 1) * 16;
      const float* bp = peK + (size_t)(bc + n) * 256 + k0 + ks;
      u16x8 v0, v1;
#pragma unroll
      for (int j = 0; j < 8; ++j) { v0[j] = f2bf(bp[j]); v1[j] = f2bf(bp[8 + j]); }
      *(u16x8*)&Bs[n][ks] = v0;
      *(u16x8*)&Bs[n][ks + 8] = v1;
    }
    __syncthreads();
    s16x8 a_frag[2], b_frag[4];
#pragma unroll
    for (int i = 0; i < 2; ++i) a_frag[i] = *(s16x8*)&As[wm + i * 16 + lid][lg * 8];
#pragma unroll
    for (int j = 0; j < 4; ++j) b_frag[j] = *(s16x8*)&Bs[wn + j * 16 + lid][lg * 8];
#pragma unroll
    for (int i = 0; i < 2; ++i)
#pragma unroll
      for (int j = 0; j < 4; ++j)
        acc[i][j] = __builtin_amdgcn_mfma_f32_16x16x32_bf16(a_frag[i], b_frag[j], acc[i][j], 0, 0, 0);
    __syncthreads();
  }
#pragma unroll
  for (int i = 0; i < 2; ++i) {
#pragma unroll
    for (int rr = 0; rr < 4; ++rr) {
      int row = wm + i * 16 + lg * 4 + rr;
#pragma unroll
      for (int j = 0; j < 4; ++j) {
        int col = wn + j * 16 + lid;
        sig[row][col] = 1.f / (1.f + __expf(-acc[i][j][rr]));
      }
    }
  }
  __syncthreads();
  float err = 0.f;
#pragma unroll
  for (int it = 0; it < 8; ++it) {
    int idx = tid + it * 256;
    int rr = idx >> 5, c4 = idx & 31;
    float4 s4 = *(const float4*)&sig[rr][c4 * 4];
    size_t o = (size_t)(br + rr) * 4096 + bc + c4 * 4;
#pragma unroll
    for (int q = 0; q < 4; ++q) {
      float4 a = *(const float4*)&A4[(size_t)q * 16777216 + o];
      float d0 = s4.x - a.x, d1 = s4.y - a.y, d2 = s4.z - a.z, d3 = s4.w - a.w;
      err += d0 * d0 + d1 * d1 + d2 * d2 + d3 * d3;
    }
  }
  red[tid] = err;
  __syncthreads();
  for (int o = 128; o; o >>= 1){
    if (tid < o) red[tid] += red[tid + o];
    __syncthreads();
  }
  if (tid == 0) atomicAdd(lossAcc, red[0]);
}

// D2 mega-GEMM + PE loss co-dispatch: blocks [0,gemmTiles) run GEMM, rest run loss.
__global__ __launch_bounds__(256) void d2loss_k(GDescArr da, int gemmTiles,
    const float* __restrict__ peQ, const float* __restrict__ peK,
    const float* __restrict__ A4, float* __restrict__ lossAcc)
{
  __shared__ __align__(16) char smem[49152];
  if ((int)blockIdx.x < gemmTiles) multi_gemm_body(da, blockIdx.x, smem);
  else loss_body(blockIdx.x - gemmTiles, smem, peQ, peK, A4, lossAcc);
}

// ---------------------------------------------------------------- prep
__global__ void prep_k(const float* __restrict__ gat1_b, const float* __restrict__ gat1_W,
                       const float* __restrict__ Wq, const float* __restrict__ bq,
                       const float* __restrict__ Wk, const float* __restrict__ bk,
                       const float* __restrict__ Wv, const float* __restrict__ bv,
                       const float* __restrict__ peWQ, const float* __restrict__ peWK,
                       const int* __restrict__ deg,
                       const float* __restrict__ gat1_as, const float* __restrict__ gat1_ad,
                       const int* __restrict__ ap_dst, const int* __restrict__ tp_dst,
                       const int* __restrict__ pa_dst,
                       const float* __restrict__ gt_Wo, const float* __restrict__ gt_Wf1,
                       const float* __restrict__ gt_Wf2, const float* __restrict__ cat_W,
                       const float* __restrict__ mlp_W1,
                       float* __restrict__ bsum, float* __restrict__ Wqkv,
                       float* __restrict__ bqkv, float* __restrict__ peW,
                       float* __restrict__ Bstack, float* __restrict__ dbv,
                       float* __restrict__ Ps, float* __restrict__ Pd,
                       int* __restrict__ cnt,
                       ushort_t* __restrict__ Wot, ushort_t* __restrict__ Wf1t,
                       ushort_t* __restrict__ Wf2t, ushort_t* __restrict__ catt,
                       ushort_t* __restrict__ mlp1t, ushort_t* __restrict__ Wqkvt)
{
  int idx = blockIdx.x * blockDim.x + threadIdx.x;
  if (idx < 1024) { bsum[idx] = gat1_b[idx] + gat1_b[3 * 1024 + idx]; return; }
  idx -= 1024;
  if (idx < 2 * 128 * 384) {
    int l = idx / 49152, rem = idx % 49152;
    int k = rem / 384, c = rem % 384;
    float v;
    if (c < 128)      v = Wq[(size_t)l * 16384 + k * 128 + c];
    else if (c < 256) v = Wk[(size_t)l * 16384 + k * 128 + c - 128];
    else              v = Wv[(size_t)l * 16384 + k * 128 + c - 256];
    Wqkv[(size_t)l * 49152 + k * 384 + c] = v;
    return;
  }
  idx -= 2 * 128 * 384;
  if (idx < 2 * 384) {
    int l = idx / 384, c = idx % 384;
    float v;
    if (c < 128)      v = bq[l * 128 + c];
    else if (c < 256) v = bk[l * 128 + c - 128];
    else              v = bv[l * 128 + c - 256];
    bqkv[l * 384 + c] = v;
    return;
  }
  idx -= 2 * 384;
  if (idx < 128 * 256) {
    int k = idx / 256, c = idx % 256;
    peW[k * 256 + c] = (c < 128) ? peWQ[k * 128 + c] : peWK[k * 128 + c - 128];
    return;
  }
  idx -= 128 * 256;
  if (idx < 256 * 1024) {
    int k = idx / 1024, c = idx % 1024;
    Bstack[idx] = (k < 128) ? gat1_W[(size_t)k * 1024 + c]
                            : gat1_W[(size_t)3 * 131072 + (size_t)(k - 128) * 1024 + c];
    return;
  }
  idx -= 256 * 1024;
  if (idx < NA) { dbv[idx] = logf(fmaxf((float)deg[idx], 1.f)); return; }
  idx -= NA;
  if (idx < 3 * 1024) {
    const int wsel[3] = {0, 3, 1};
    int type = idx / 1024, rem = idx % 1024;
    int k = rem >> 3, h = rem & 7;
    const float* wr = gat1_W + (size_t)wsel[type] * 131072 + (size_t)k * 1024 + h * 128;
    const float* a1 = gat1_as + wsel[type] * 1024 + h * 128;
    const float* a2 = gat1_ad + wsel[type] * 1024 + h * 128;
    float s1 = 0.f, s2 = 0.f;
    for (int c = 0; c < 128; ++c){ float wv = wr[c]; s1 = fmaf(wv, a1[c], s1); s2 = fmaf(wv, a2[c], s2); }
    Ps[(size_t)type * 1024 + k * 8 + h] = s1;
    Pd[(size_t)type * 1024 + k * 8 + h] = s2;
    return;
  }
  idx -= 3 * 1024;
  if (idx < E_TOT) {
    int slot;
    if (idx < E_AP)             slot = ap_dst[idx];
    else if (idx < E_AP + E_TP) slot = NPA + tp_dst[idx - E_AP];
    else                        slot = 2 * NPA + pa_dst[idx - E_AP - E_TP];
    atomicAdd(&cnt[slot], 1);
    return;
  }
  idx -= E_TOT;
  if (idx < 2 * 128 * 128) {
    int l = idx / 16384, rem = idx % 16384;
    int n = rem / 128, k = rem % 128;
    Wot[idx] = f2bf(gt_Wo[(size_t)l * 16384 + k * 128 + n]);
    return;
  }
  idx -= 2 * 128 * 128;
  if (idx < 2 * 256 * 128) {
    int l = idx / 32768, rem = idx % 32768;
    int n = rem / 128, k = rem % 128;
    Wf1t[idx] = f2bf(gt_Wf1[(size_t)l * 32768 + k * 256 + n]);
    return;
  }
  idx -= 2 * 256 * 128;
  if (idx < 2 * 128 * 256) {
    int l = idx / 32768, rem = idx % 32768;
    int n = rem / 256, k = rem % 256;
    Wf2t[idx] = f2bf(gt_Wf2[(size_t)l * 32768 + k * 128 + n]);
    return;
  }
  idx -= 2 * 128 * 256;
  if (idx < 128 * 384) {
    int n = idx / 384, k = idx % 384;
    catt[idx] = f2bf(cat_W[(size_t)k * 128 + n]);
    return;
  }
  idx -= 128 * 384;
  if (idx < 256 * 128) {
    int n = idx / 128, k = idx % 128;
    mlp1t[idx] = f2bf(mlp_W1[(size_t)k * 256 + n]);
    return;
  }
  idx -= 256 * 128;
  if (idx < 2 * 384 * 128) {
    int l = idx / 49152, rem = idx % 49152;
    int n = rem / 128, k = rem % 128;
    float v;
    if (n < 128)      v = Wq[(size_t)l * 16384 + k * 128 + n];
    else if (n < 256) v = Wk[(size_t)l * 16384 + k * 128 + n - 128];
    else              v = Wv[(size_t)l * 16384 + k * 128 + n - 256];
    Wqkvt[idx] = f2bf(v);
  }
}

// ---------------------------------------------------------------- exscan (1 block, 1024 thr)
__global__ __launch_bounds__(1024) void exscan_k(const int* __restrict__ in, int* __restrict__ out, int n){
  __shared__ int wsum[16];
  __shared__ int carrySh;
  int t = threadIdx.x, w = t >> 6, lane = t & 63;
  if (t == 0) carrySh = 0;
  __syncthreads();
  for (int base = 0; base < n; base += 1024){
    int carry = carrySh;
    int v = (base + t < n) ? in[base + t] : 0;
    int sc = v;
#pragma unroll
    for (int o2 = 1; o2 < 64; o2 <<= 1){
      int u = __shfl_up(sc, o2);
      if (lane >= o2) sc += u;
    }
    if (lane == 63) wsum[w] = sc;
    __syncthreads();
    int wadd = 0;
#pragma unroll
    for (int i = 0; i < 15; ++i) if (i < w) wadd += wsum[i];
    if (base + t < n) out[base + t] = carry + wadd + sc - v;
    if (t == 1023) carrySh = carry + wadd + sc;
    __syncthreads();
  }
}

// ---------------------------------------------------------------- scorev + scatter co-dispatch
__global__ __launch_bounds__(256) void score_scatter_k(
    const ushort_t* __restrict__ xa, const ushort_t* __restrict__ xp, const ushort_t* __restrict__ xt,
    const float* __restrict__ Ps, const float* __restrict__ Pd, float* __restrict__ scores,
    const int* __restrict__ ap_dst, const int* __restrict__ tp_dst, const int* __restrict__ pa_dst,
    const int* __restrict__ off, int* __restrict__ cur, int* __restrict__ eidx)
{
  if ((int)blockIdx.x < SCV_BLOCKS) {
    int r = blockIdx.x * 4 + (threadIdx.x >> 6);
    int lane = threadIdx.x & 63;
    const ushort_t* x; const float* P; int row;
    if (r < 4096)       { x = xa; P = Ps;        row = r; }
    else if (r < 12288) { x = xp; P = Pd;        row = r - 4096; }
    else if (r < 16384) { x = xt; P = Ps + 1024; row = r - 12288; }
    else if (r < 24576) { x = xp; P = Pd + 1024; row = r - 16384; }
    else if (r < 32768) { x = xp; P = Ps + 2048; row = r - 24576; }
    else                { x = xa; P = Pd + 2048; row = r - 32768; }
    unsigned u = *(const unsigned*)(x + (size_t)row * 128 + 2 * lane);
    float x0 = bf2f((ushort_t)(u & 0xffff));
    float x1 = bf2f((ushort_t)(u >> 16));
    float res[8];
#pragma unroll
    for (int h = 0; h < 8; ++h) {
      float s = x0 * P[(2 * lane) * 8 + h] + x1 * P[(2 * lane + 1) * 8 + h];
#pragma unroll
      for (int o = 32; o; o >>= 1) s += __shfl_down(s, o);
      res[h] = s;
    }
    if (lane == 0) {
#pragma unroll
      for (int h = 0; h < 8; ++h) scores[(size_t)r * 8 + h] = res[h];
    }
  } else {
    int i = (blockIdx.x - SCV_BLOCKS) * 256 + threadIdx.x;
    if (i >= E_TOT) return;
    int slot, local;
    if (i < E_AP)             { local = i;                 slot = ap_dst[local]; }
    else if (i < E_AP + E_TP) { local = i - E_AP;          slot = NPA + tp_dst[local]; }
    else                      { local = i - E_AP - E_TP;   slot = 2 * NPA + pa_dst[local]; }
    int p = atomicAdd(&cur[slot], 1);
    eidx[off[slot] + p] = local;
  }
}

// ---------------------------------------------------------------- GAT aggregation kernels
__global__ __launch_bounds__(256) void agg8ff_k(
    const int* __restrict__ eidx, const int* __restrict__ off, const int* __restrict__ cnt,
    const int* __restrict__ ap_src, const int* __restrict__ tp_src, const int* __restrict__ pa_src,
    const ushort_t* __restrict__ xa, const ushort_t* __restrict__ xt, const ushort_t* __restrict__ xp,
    const float* __restrict__ scores, ushort_t* __restrict__ agg)
{
  int g = blockIdx.x * 4 + (threadIdx.x >> 6);
  if (g >= NSLOT) return;
  const int* src; const ushort_t* x; const float* ssb; const float* sdb; int d;
  if (g < NPA)          { src = ap_src; x = xa; ssb = scores;                     sdb = scores + (size_t)4096 * 8;  d = g; }
  else if (g < 2 * NPA) { src = tp_src; x = xt; ssb = scores + (size_t)12288 * 8; sdb = scores + (size_t)16384 * 8; d = g - NPA; }
  else                  { src = pa_src; x = xp; ssb = scores + (size_t)24576 * 8; sdb = scores + (size_t)32768 * 8; d = g - 2 * NPA; }
  int lane = threadIdx.x & 63;
  int hh = lane & 7;
  float sdv = sdb[(size_t)d * 8 + hh];
  int base = off[g], n = cnt[g];
  float mh = -1e30f, den = 0.f;
  float acc0[8], acc1[8];
#pragma unroll
  for (int h2 = 0; h2 < 8; ++h2){ acc0[h2] = 0.f; acc1[h2] = 0.f; }
  int e = (n > 0) ? eidx[base] : 0;
  int s = (n > 0) ? src[e] : 0;
  for (int k = 0; k < n; ++k){
    int en = 0, sn = 0;
    if (k + 1 < n){ en = eidx[base + k + 1]; sn = src[en]; }
    float v = ssb[(size_t)s * 8 + hh] + sdv;
    v = v > 0.f ? v : 0.2f * v;
    float mn = fmaxf(mh, v);
    float sc = __expf(mh - mn);
    float wv_ = __expf(v - mn);
    den = den * sc + wv_;
    mh = mn;
    unsigned u = *(const unsigned*)(x + (size_t)s * 128 + 2 * lane);
    float xv0 = bf2f((ushort_t)(u & 0xffff));
    float xv1 = bf2f((ushort_t)(u >> 16));
#pragma unroll
    for (int h2 = 0; h2 < 8; ++h2){
      float sch = __shfl(sc, h2);
      float wh = __shfl(wv_, h2);
      acc0[h2] = fmaf(wh, xv0, acc0[h2] * sch);
      acc1[h2] = fmaf(wh, xv1, acc1[h2] * sch);
    }
    e = en; s = sn;
  }
  ushort_t* o = agg + (size_t)g * 1024;
#pragma unroll
  for (int h2 = 0; h2 < 8; ++h2){
    float dh = __shfl(den, h2) + 1e-16f;
    unsigned pk = (unsigned)f2bf(acc0[h2] / dh) | ((unsigned)f2bf(acc1[h2] / dh) << 16);
    *(unsigned*)(o + h2 * 128 + 2 * lane) = pk;
  }
}

__global__ __launch_bounds__(256) void gat_agg1f_k(
    const int* __restrict__ eidx, const int* __restrict__ off, const int* __restrict__ cnt,
    const int* __restrict__ src, const ushort_t* __restrict__ hs,
    const float* __restrict__ sArr,
    const float* __restrict__ bias, float* __restrict__ outp, int Ndst)
{
  int d = blockIdx.x * 4 + (threadIdx.x >> 6);
  if (d >= Ndst) return;
  int lane = threadIdx.x & 63;
  float sdv = sArr[8192 + d];
  int base = off[d], n = cnt[d];
  float mh = -1e30f, den = 0.f, a0 = 0.f, a1 = 0.f;
  int e = (n > 0) ? eidx[base] : 0;
  int s = (n > 0) ? src[e] : 0;
  for (int k = 0; k < n; ++k){
    int en = 0, sn = 0;
    if (k + 1 < n){ en = eidx[base + k + 1]; sn = src[en]; }
    float v = sArr[s] + sdv;
    v = v > 0.f ? v : 0.2f * v;
    float mn = fmaxf(mh, v);
    float sc = __expf(mh - mn);
    float w_ = __expf(v - mn);
    den = den * sc + w_;
    mh = mn;
    unsigned u = *(const unsigned*)(hs + (size_t)s * 128 + 2 * lane);
    a0 = fmaf(w_, bf2f((ushort_t)(u & 0xffff)), a0 * sc);
    a1 = fmaf(w_, bf2f((ushort_t)(u >> 16)), a1 * sc);
    e = en; s = sn;
  }
  float inv = 1.f / (den + 1e-16f);
  outp[(size_t)d * 128 + 2 * lane]     = a0 * inv + bias[2 * lane];
  outp[(size_t)d * 128 + 2 * lane + 1] = a1 * inv + bias[2 * lane + 1];
}

// ---------------------------------------------------------------- MFMA flash attention (bf16 QKV packed, ld=384)
__global__ __launch_bounds__(256) void attn_mfma_k(
    const ushort_t* __restrict__ Q, const ushort_t* __restrict__ K, const ushort_t* __restrict__ V,
    const float* __restrict__ dbv, float* __restrict__ part)
{
  const int ld = 384;
  int h = blockIdx.y, sp = blockIdx.z;
  int qbase = blockIdx.x * 64;
  int tid = threadIdx.x;
  int w = tid >> 6, lane = tid & 63, lid = lane & 15, lg = lane >> 4;
  __shared__ __align__(16) ushort_t Vt[16][72];
  __shared__ __align__(16) ushort_t Pl[4][16][72];
  __shared__ float dbs[64];

  s16x8 qf;
  if (lg < 2) {
    u16x8 v = *(const u16x8*)(Q + (size_t)(qbase + 16 * w + lid) * ld + h * 16 + 8 * lg);
#pragma unroll
    for (int j = 0; j < 8; ++j) v[j] = f2bf(bf2f(v[j]) * 0.25f);
    qf = (s16x8)v;
  } else {
    qf = (s16x8){0,0,0,0,0,0,0,0};
  }

  float m = -1e30f, l = 0.f;
  f32x4 o = {0.f, 0.f, 0.f, 0.f};

  int kb0 = sp * (4096 / ASPLIT);
  for (int kt = 0; kt < 4096 / ASPLIT; kt += 64) {
    int kb = kb0 + kt;
    __syncthreads();
    {
      int key = tid >> 2, ds_ = (tid & 3) * 4;
      const ushort_t* vp = V + (size_t)(kb + key) * ld + h * 16 + ds_;
#pragma unroll
      for (int j = 0; j < 4; ++j) Vt[ds_ + j][key] = vp[j];
      if (tid < 64) dbs[tid] = dbv[kb + tid];
    }
    __syncthreads();

    f32x4 s[4];
#pragma unroll
    for (int g = 0; g < 4; ++g) {
      s16x8 kf;
      if (lg < 2) {
        kf = (s16x8)(*(const u16x8*)(K + (size_t)(kb + 16 * g + lid) * ld + h * 16 + 8 * lg));
      } else kf = (s16x8){0,0,0,0,0,0,0,0};
      s[g] = __builtin_amdgcn_mfma_f32_16x16x32_bf16(kf, qf, (f32x4){0.f,0.f,0.f,0.f}, 0, 0, 0);
    }
#pragma unroll
    for (int g = 0; g < 4; ++g)
#pragma unroll
      for (int r = 0; r < 4; ++r) s[g][r] += dbs[16 * g + 4 * lg + r];

    float tmax = -1e30f;
#pragma unroll
    for (int g = 0; g < 4; ++g)
#pragma unroll
      for (int r = 0; r < 4; ++r) tmax = fmaxf(tmax, s[g][r]);
    tmax = fmaxf(tmax, __shfl_xor(tmax, 16));
    tmax = fmaxf(tmax, __shfl_xor(tmax, 32));
    float mn = fmaxf(m, tmax);
    float scale = __expf(m - mn);
    float psum = 0.f;
    float p[4][4];
#pragma unroll
    for (int g = 0; g < 4; ++g)
#pragma unroll
      for (int r = 0; r < 4; ++r) { p[g][r] = __expf(s[g][r] - mn); psum += p[g][r]; }
    psum += __shfl_xor(psum, 16);
    psum += __shfl_xor(psum, 32);
    l = l * scale + psum;
    m = mn;

#pragma unroll
    for (int g = 0; g < 4; ++g) {
#pragma unroll
      for (int rp = 0; rp < 4; rp += 2) {
        unsigned pack = (unsigned)f2bf(p[g][rp]) | ((unsigned)f2bf(p[g][rp + 1]) << 16);
        *(unsigned*)&Pl[w][lid][16 * g + 4 * lg + rp] = pack;
      }
    }
#pragma unroll
    for (int r = 0; r < 4; ++r) o[r] *= __shfl(scale, 4 * lg + r);
#pragma unroll
    for (int kc = 0; kc < 2; ++kc) {
      s16x8 pa = *(s16x8*)&Pl[w][lid][32 * kc + 8 * lg];
      s16x8 vb = *(s16x8*)&Vt[lid][32 * kc + 8 * lg];
      o = __builtin_amdgcn_mfma_f32_16x16x32_bf16(pa, vb, o, 0, 0, 0);
    }
  }
  float* pb = part + ((size_t)(sp * 8 + h) * NA) * 18;
#pragma unroll
  for (int r = 0; r < 4; ++r) {
    int qq = qbase + 16 * w + 4 * lg + r;
    pb[(size_t)qq * 18 + lid] = o[r];
  }
  if (lg == 0) {
    int qq = qbase + 16 * w + lid;
    pb[(size_t)qq * 18 + 16] = m;
    pb[(size_t)qq * 18 + 17] = l;
  }
}

// ---------------------------------------------------------------- fused transformer tail (templated)
// MODE 0: combine->Wo->LN1->FF1->FF2->LN2 -> write outX f32 AND next-layer QKVb (bf16, via Wqkvt)
// MODE 1: same through LN2, then head: concat(hA2|o1|X) -> cat relu (x_gt) -> mlp1 relu -> mlp2+softmax
template<int MODE>
__global__ __launch_bounds__(256) void gt_tail_k(
    const float* __restrict__ part,
    const ushort_t* __restrict__ Wot, const float* __restrict__ bo,
    const float* __restrict__ xin,
    const float* __restrict__ g1, const float* __restrict__ be1,
    const ushort_t* __restrict__ Wf1t, const float* __restrict__ bf1,
    const ushort_t* __restrict__ Wf2t, const float* __restrict__ bf2,
    const float* __restrict__ g2, const float* __restrict__ be2,
    float* __restrict__ outX,
    const ushort_t* __restrict__ Wqkvt, const float* __restrict__ bqkv,
    const float* __restrict__ peQK, ushort_t* __restrict__ QKVb,
    const float* __restrict__ hA2, const float* __restrict__ o1,
    const ushort_t* __restrict__ catt, const float* __restrict__ cat_b,
    const ushort_t* __restrict__ mlp1t, const float* __restrict__ mlp_b1,
    const float* __restrict__ mlp_W2, const float* __restrict__ mlp_b2,
    const float* __restrict__ lossAcc, float* __restrict__ out)
{
  constexpr int AW = (MODE == 1) ? 392 : 136;
  __shared__ __align__(16) ushort_t Aly[16][AW];
  __shared__ __align__(16) ushort_t Bs[256][40];
  __shared__ __align__(16) ushort_t F1b[16][264];
  __shared__ float X1[16][132];
  __shared__ float LG[16][4];
  int bm = blockIdx.x * 16;
  int tid = threadIdx.x;
  int w = tid >> 6, lane = tid & 63, lg = lane >> 4, lid = lane & 15;
  if (MODE == 1 && blockIdx.x == 0 && tid == 0) out[0] = lossAcc[0] * (1.0f / 67108864.0f);

  // phase 0: split-attention combine -> O bf16 (16 x 128)
  {
    int row = bm + (tid >> 4);
    int seg = tid & 15;
    int kcol = seg * 8;
    int h = kcol >> 4, d0 = kcol & 15;
    float mm = -1e30f;
#pragma unroll
    for (int sp = 0; sp < ASPLIT; ++sp)
      mm = fmaxf(mm, part[((size_t)(sp * 8 + h) * NA + row) * 18 + 16]);
    float ll = 0.f, a[8];
#pragma unroll
    for (int j = 0; j < 8; ++j) a[j] = 0.f;
#pragma unroll
    for (int sp = 0; sp < ASPLIT; ++sp){
      const float* pp = part + ((size_t)(sp * 8 + h) * NA + row) * 18;
      float wq = __expf(pp[16] - mm);
      ll += pp[17] * wq;
#pragma unroll
      for (int j = 0; j < 8; ++j) a[j] = fmaf(pp[d0 + j], wq, a[j]);
    }
    float inv = 1.f / ll;
    u16x8 v;
#pragma unroll
    for (int j = 0; j < 8; ++j) v[j] = f2bf(a[j] * inv);
    *(u16x8*)&Aly[tid >> 4][kcol] = v;
  }
  __syncthreads();

  // phase 1: O @ Wo + bo + xin -> X1, LN1 -> Aly bf16 + X1 f32
  f32x4 acc1[2];
  acc1[0] = (f32x4){0.f,0.f,0.f,0.f};
  acc1[1] = (f32x4){0.f,0.f,0.f,0.f};
  for (int k0 = 0; k0 < 128; k0 += 32){
    int n = tid >> 1, ks = (tid & 1) * 16;
    *(u16x8*)&Bs[n][ks]     = *(const u16x8*)(Wot + (size_t)n * 128 + k0 + ks);
    *(u16x8*)&Bs[n][ks + 8] = *(const u16x8*)(Wot + (size_t)n * 128 + k0 + ks + 8);
    __syncthreads();
    s16x8 af = *(s16x8*)&Aly[lid][k0 + lg * 8];
#pragma unroll
    for (int j = 0; j < 2; ++j){
      s16x8 bf = *(s16x8*)&Bs[w * 32 + j * 16 + lid][lg * 8];
      acc1[j] = __builtin_amdgcn_mfma_f32_16x16x32_bf16(af, bf, acc1[j], 0, 0, 0);
    }
    __syncthreads();
  }
#pragma unroll
  for (int j = 0; j < 2; ++j)
#pragma unroll
    for (int rr = 0; rr < 4; ++rr){
      int r = lg * 4 + rr, c = w * 32 + j * 16 + lid;
      X1[r][c] = acc1[j][rr] + bo[c] + xin[(size_t)(bm + r) * 128 + c];
    }
  __syncthreads();
  {
    int r = tid >> 4, p = tid & 15;
    float s = 0.f, q = 0.f;
#pragma unroll
    for (int j = 0; j < 8; ++j){ float v = X1[r][p * 8 + j]; s += v; q += v * v; }
#pragma unroll
    for (int mk = 1; mk < 16; mk <<= 1){ s += __shfl_xor(s, mk); q += __shfl_xor(q, mk); }
    float mean = s * (1.f / 128.f), var = q * (1.f / 128.f) - mean * mean;
    float inv = rsqrtf(var + 1e-5f);
    u16x8 v;
#pragma unroll
    for (int j = 0; j < 8; ++j){
      int c = p * 8 + j;
      float f = (X1[r][c] - mean) * inv * g1[c] + be1[c];
      X1[r][c] = f;
      v[j] = f2bf(f);
    }
    *(u16x8*)&Aly[r][p * 8] = v;
  }
  __syncthreads();

  // phase 2: x1 @ Wf1 + bf1, relu -> F1b (16 x 256)
  f32x4 acc2[4];
#pragma unroll
  for (int j = 0; j < 4; ++j) acc2[j] = (f32x4){0.f,0.f,0.f,0.f};
  for (int k0 = 0; k0 < 128; k0 += 32){
#pragma unroll
    for (int q4 = 0; q4 < 4; ++q4)
      *(u16x8*)&Bs[tid][q4 * 8] = *(const u16x8*)(Wf1t + (size_t)tid * 128 + k0 + q4 * 8);
    __syncthreads();
    s16x8 af = *(s16x8*)&Aly[lid][k0 + lg * 8];
#pragma unroll
    for (int j = 0; j < 4; ++j){
      s16x8 bf = *(s16x8*)&Bs[w * 64 + j * 16 + lid][lg * 8];
      acc2[j] = __builtin_amdgcn_mfma_f32_16x16x32_bf16(af, bf, acc2[j], 0, 0, 0);
    }
    __syncthreads();
  }
#pragma unroll
  for (int j = 0; j < 4; ++j)
#pragma unroll
    for (int rr = 0; rr < 4; ++rr){
      int r = lg * 4 + rr, c = w * 64 + j * 16 + lid;
      F1b[r][c] = f2bf(fmaxf(acc2[j][rr] + bf1[c], 0.f));
    }
  __syncthreads();

  // phase 3: f1 @ Wf2 + bf2 + X1 -> LN2 -> X1 (normalized) [+ outX in MODE 0]
  f32x4 acc3[2];
  acc3[0] = (f32x4){0.f,0.f,0.f,0.f};
  acc3[1] = (f32x4){0.f,0.f,0.f,0.f};
  for (int k0 = 0; k0 < 256; k0 += 32){
    int n = tid >> 1, ks = (tid & 1) * 16;
    *(u16x8*)&Bs[n][ks]     = *(const u16x8*)(Wf2t + (size_t)n * 256 + k0 + ks);
    *(u16x8*)&Bs[n][ks + 8] = *(const u16x8*)(Wf2t + (size_t)n * 256 + k0 + ks + 8);
    __syncthreads();
    s16x8 af = *(s16x8*)&F1b[lid][k0 + lg * 8];
#pragma unroll
    for (int j = 0; j < 2; ++j){
      s16x8 bf = *(s16x8*)&Bs[w * 32 + j * 16 + lid][lg * 8];
      acc3[j] = __builtin_amdgcn_mfma_f32_16x16x32_bf16(af, bf, acc3[j], 0, 0, 0);
    }
    __syncthreads();
  }
#pragma unroll
  for (int j = 0; j < 2; ++j)
#pragma unroll
    for (int rr = 0; rr < 4; ++rr){
      int r = lg * 4 + rr, c = w * 32 + j * 16 + lid;
      X1[r][c] = acc3[j][rr] + bf2[c] + X1[r][c];
    }
  __syncthreads();
  {
    int r = tid >> 4, p = tid & 15;
    float s = 0.f, q = 0.f;
#pragma unroll
    for (int j = 0; j < 8; ++j){ float v = X1[r][p * 8 + j]; s += v; q += v * v; }
#pragma unroll
    for (int mk = 1; mk < 16; mk <<= 1){ s += __shfl_xor(s, mk); q += __shfl_xor(q, mk); }
    float mean = s * (1.f / 128.f), var = q * (1.f / 128.f) - mean * mean;
    float inv = rsqrtf(var + 1e-5f);
    u16x8 v;
#pragma unroll
    for (int j = 0; j < 8; ++j){
      int c = p * 8 + j;
      float f = (X1[r][c] - mean) * inv * g2[c] + be2[c];
      X1[r][c] = f;
      v[j] = f2bf(f);
      if (MODE == 0) outX[(size_t)(bm + r) * 128 + c] = f;
    }
    if (MODE == 0) *(u16x8*)&Aly[r][p * 8] = v;
    else           *(u16x8*)&Aly[r][256 + p * 8] = v;
  }
  __syncthreads();

  if constexpr (MODE == 0) {
    // phase 4: X @ Wqkvt (N=384) + bqkv + peQK(cols<256) -> QKVb bf16
#pragma unroll
    for (int nb = 0; nb < 2; ++nb) {
      f32x4 acc4[3];
#pragma unroll
      for (int j = 0; j < 3; ++j) acc4[j] = (f32x4){0.f,0.f,0.f,0.f};
      for (int k0 = 0; k0 < 128; k0 += 32){
#pragma unroll
        for (int p = 0; p < 3; ++p){
          int idx = tid + p * 256;
          int n = idx >> 2, seg = (idx & 3) * 8;
          *(u16x8*)&Bs[n][seg] = *(const u16x8*)(Wqkvt + (size_t)(nb * 192 + n) * 128 + k0 + seg);
        }
        __syncthreads();
        s16x8 af = *(s16x8*)&Aly[lid][k0 + lg * 8];
#pragma unroll
        for (int j = 0; j < 3; ++j){
          s16x8 bf = *(s16x8*)&Bs[w * 48 + j * 16 + lid][lg * 8];
          acc4[j] = __builtin_amdgcn_mfma_f32_16x16x32_bf16(af, bf, acc4[j], 0, 0, 0);
        }
        __syncthreads();
      }
#pragma unroll
      for (int j = 0; j < 3; ++j)
#pragma unroll
        for (int rr = 0; rr < 4; ++rr){
          int r = lg * 4 + rr, c = nb * 192 + w * 48 + j * 16 + lid;
          float v = acc4[j][rr] + bqkv[c];
          if (c < 256) v += peQK[(size_t)(bm + r) * 256 + c];
          QKVb[(size_t)(bm + r) * 384 + c] = f2bf(v);
        }
    }
  } else {
    // phase 4': head
    {
      int r = bm + (tid >> 4), seg = tid & 15;
#pragma unroll
      for (int ch = 0; ch < 2; ++ch){
        int c0 = seg * 16 + ch * 8;
        const float* src; int cc;
        if (c0 < 128) { src = hA2; cc = c0; }
        else          { src = o1;  cc = c0 - 128; }
        u16x8 v;
#pragma unroll
        for (int j = 0; j < 8; ++j) v[j] = f2bf(src[(size_t)r * 128 + cc + j]);
        *(u16x8*)&Aly[tid >> 4][c0] = v;
      }
    }
    __syncthreads();
    float* xgt = out + 1 + NA * 4;
    f32x4 acc1b[2];
    acc1b[0] = (f32x4){0.f,0.f,0.f,0.f};
    acc1b[1] = (f32x4){0.f,0.f,0.f,0.f};
    for (int k0 = 0; k0 < 384; k0 += 32){
      int n = tid >> 1, ks = (tid & 1) * 16;
      *(u16x8*)&Bs[n][ks]     = *(const u16x8*)(catt + (size_t)n * 384 + k0 + ks);
      *(u16x8*)&Bs[n][ks + 8] = *(const u16x8*)(catt + (size_t)n * 384 + k0 + ks + 8);
      __syncthreads();
      s16x8 af = *(s16x8*)&Aly[lid][k0 + lg * 8];
#pragma unroll
      for (int j = 0; j < 2; ++j){
        s16x8 bf = *(s16x8*)&Bs[w * 32 + j * 16 + lid][lg * 8];
        acc1b[j] = __builtin_amdgcn_mfma_f32_16x16x32_bf16(af, bf, acc1b[j], 0, 0, 0);
      }
      __syncthreads();
    }
#pragma unroll
    for (int j = 0; j < 2; ++j)
#pragma unroll
      for (int rr = 0; rr < 4; ++rr){
        int r = lg * 4 + rr, c = w * 32 + j * 16 + lid;
        float f = fmaxf(acc1b[j][rr] + cat_b[c], 0.f);
        xgt[(size_t)(bm + r) * 128 + c] = f;
        Aly[r][c] = f2bf(f);
      }
    __syncthreads();
    f32x4 acc2b[4];
#pragma unroll
    for (int j = 0; j < 4; ++j) acc2b[j] = (f32x4){0.f,0.f,0.f,0.f};
    for (int k0 = 0; k0 < 128; k0 += 32){
#pragma unroll
      for (int q4 = 0; q4 < 4; ++q4)
        *(u16x8*)&Bs[tid][q4 * 8] = *(const u16x8*)(mlp1t + (size_t)tid * 128 + k0 + q4 * 8);
      __syncthreads();
      s16x8 af = *(s16x8*)&Aly[lid][k0 + lg * 8];
#pragma unroll
      for (int j = 0; j < 4; ++j){
        s16x8 bf = *(s16x8*)&Bs[w * 64 + j * 16 + lid][lg * 8];
        acc2b[j] = __builtin_amdgcn_mfma_f32_16x16x32_bf16(af, bf, acc2b[j], 0, 0, 0);
      }
      __syncthreads();
    }
#pragma unroll
    for (int j = 0; j < 4; ++j)
#pragma unroll
      for (int rr = 0; rr < 4; ++rr){
        int r = lg * 4 + rr, c = w * 64 + j * 16 + lid;
        F1b[r][c] = f2bf(fmaxf(acc2b[j][rr] + mlp_b1[c], 0.f));
      }
    __syncthreads();
    {
      int r = tid >> 4, rem = tid & 15, c = rem >> 2, p = rem & 3;
      float s = 0.f;
      for (int k = p * 64; k < p * 64 + 64; ++k)
        s = fmaf(bf2f(F1b[r][k]), mlp_W2[(size_t)k * 4 + c], s);
      s += __shfl_xor(s, 1);
      s += __shfl_xor(s, 2);
      if (p == 0) LG[r][c] = s + mlp_b2[c];
    }
    __syncthreads();
    if (tid < 16){
      int r = tid;
      float l0 = LG[r][0], l1 = LG[r][1], l2 = LG[r][2], l3 = LG[r][3];
      float mx = fmaxf(fmaxf(l0, l1), fmaxf(l2, l3));
      float e0 = __expf(l0 - mx), e1 = __expf(l1 - mx), e2 = __expf(l2 - mx), e3 = __expf(l3 - mx);
      float inv = 1.f / (e0 + e1 + e2 + e3);
      float* o = out + 1 + (size_t)(bm + r) * 4;
      o[0] = e0 * inv; o[1] = e1 * inv; o[2] = e2 * inv; o[3] = e3 * inv;
    }
  }
}

__global__ void setval_k(float* p, float v){ p[0] = v; }

// ---------------------------------------------------------------- host
extern "C" void kernel_launch(void* const* d_in, const int* in_sizes, int n_in,
                              void* d_out, int out_size, void* d_ws, size_t ws_size,
                              hipStream_t stream)
{
  (void)in_sizes; (void)n_in; (void)out_size;
  const float* x_author = (const float*)d_in[0];
  const float* x_paper  = (const float*)d_in[1];
  const float* x_term   = (const float*)d_in[2];
  const int* ap_src = (const int*)d_in[3];
  const int* ap_dst = (const int*)d_in[4];
  const int* pa_src = (const int*)d_in[5];
  const int* pa_dst = (const int*)d_in[6];
  const int* tp_src = (const int*)d_in[9];
  const int* tp_dst = (const int*)d_in[10];
  const float* original_A = (const float*)d_in[11];
  const int* deg = (const int*)d_in[12];
  const float* t1_W = (const float*)d_in[13]; const float* t1_b = (const float*)d_in[14];
  const float* t2_W = (const float*)d_in[15]; const float* t2_b = (const float*)d_in[16];
  const float* t3_W = (const float*)d_in[17]; const float* t3_b = (const float*)d_in[18];
  const float* gat1_W  = (const float*)d_in[19];
  const float* gat1_as = (const float*)d_in[20];
  const float* gat1_ad = (const float*)d_in[21];
  const float* gat1_b  = (const float*)d_in[22];
  const float* gat2_W  = (const float*)d_in[23];
  const float* gat2_as = (const float*)d_in[24];
  const float* gat2_ad = (const float*)d_in[25];
  const float* gat2_b  = (const float*)d_in[26];
  const float* pe_embed = (const float*)d_in[27];
  const float* peWQ = (const float*)d_in[28];
  const float* peWK = (const float*)d_in[29];
  const float* gt_Wq = (const float*)d_in[30]; const float* gt_bq = (const float*)d_in[31];
  const float* gt_Wk = (const float*)d_in[32]; const float* gt_bk = (const float*)d_in[33];
  const float* gt_Wv = (const float*)d_in[34]; const float* gt_bv = (const float*)d_in[35];
  const float* gt_Wo = (const float*)d_in[36]; const float* gt_bo = (const float*)d_in[37];
  const float* gt_g1 = (const float*)d_in[38]; const float* gt_be1 = (const float*)d_in[39];
  const float* gt_Wf1 = (const float*)d_in[40]; const float* gt_bf1 = (const float*)d_in[41];
  const float* gt_Wf2 = (const float*)d_in[42]; const float* gt_bf2 = (const float*)d_in[43];
  const float* gt_g2 = (const float*)d_in[44]; const float* gt_be2 = (const float*)d_in[45];
  const float* cat_W = (const float*)d_in[46]; const float* cat_b = (const float*)d_in[47];
  const float* mlp_W1 = (const float*)d_in[48]; const float* mlp_b1 = (const float*)d_in[49];
  const float* mlp_W2 = (const float*)d_in[50]; const float* mlp_b2 = (const float*)d_in[51];
  float* out = (float*)d_out;

  // ---- workspace layout ----
  char* base = (char*)d_ws;
  size_t off = 0;
  auto alloc = [&](size_t nbytes) -> void* {
    void* p = base + off;
    off += (nbytes + 255) & ~(size_t)255;
    return p;
  };
  ushort_t* xa  = (ushort_t*)alloc((size_t)NA * 128 * 2);
  ushort_t* xp  = (ushort_t*)alloc((size_t)NPA * 128 * 2);
  ushort_t* xt  = (ushort_t*)alloc((size_t)NT * 128 * 2);
  ushort_t* accP = (ushort_t*)alloc((size_t)NPA * 1024 * 2); // +accA contiguous; aliased as attn part
  ushort_t* accA = (ushort_t*)alloc((size_t)NA * 1024 * 2);
  ushort_t* agg  = (ushort_t*)alloc((size_t)NSLOT * 1024 * 2);
  float* scores = (float*)alloc((size_t)36864 * 8 * 4);
  float* Ps   = (float*)alloc(3 * 1024 * 4);
  float* Pd   = (float*)alloc(3 * 1024 * 4);
  ushort_t* hs2 = (ushort_t*)alloc((size_t)NPA * 128 * 2);   // +hd2 contiguous
  ushort_t* hd2 = (ushort_t*)alloc((size_t)NA * 128 * 2);
  float* s2sd = (float*)alloc((size_t)(NPA + NA) * 4);
  float* hA2  = (float*)alloc((size_t)NA * 128 * 4);
  float* peQK = (float*)alloc((size_t)NA * 256 * 4);
  float* dbv  = (float*)alloc((size_t)NA * 4);
  float* bsum = (float*)alloc(1024 * 4);
  float* Wqkv = (float*)alloc((size_t)2 * 128 * 384 * 4);
  float* bqkv = (float*)alloc((size_t)2 * 384 * 4);
  float* peW  = (float*)alloc((size_t)128 * 256 * 4);
  float* Bstack = (float*)alloc((size_t)256 * 1024 * 4);
  ushort_t* Wot   = (ushort_t*)alloc((size_t)2 * 128 * 128 * 2);
  ushort_t* Wf1t  = (ushort_t*)alloc((size_t)2 * 256 * 128 * 2);
  ushort_t* Wf2t  = (ushort_t*)alloc((size_t)2 * 128 * 256 * 2);
  ushort_t* catt  = (ushort_t*)alloc((size_t)128 * 384 * 2);
  ushort_t* mlp1t = (ushort_t*)alloc((size_t)256 * 128 * 2);
  ushort_t* Wqkvt = (ushort_t*)alloc((size_t)2 * 384 * 128 * 2);
  ushort_t* QKVb = (ushort_t*)alloc((size_t)NA * 384 * 2);
  float* outs1= (float*)alloc((size_t)NA * 128 * 4);
  int*   offb = (int*)alloc((size_t)NSLOT * 4);
  int*   eidx = (int*)alloc((size_t)E_TOT * 4);
  // ---- zero-init region (single small memset): cnt, cur, lossAcc ----
  size_t zstart = off;
  int*      cnt   = (int*)alloc((size_t)NSLOT * 4);
  int*      cur   = (int*)alloc((size_t)NSLOT * 4);
  float*    lossAcc = (float*)alloc(256);
  size_t zlen = off - zstart;

  float* part = (float*)accP;  // 9.4 MB f32 partials alias onto accP+accA (dead by transformer)

  if (off > ws_size){
    setval_k<<<1, 1, 0, stream>>>(out, -12345.0f);
    return;
  }

  auto gemmx = [&](int act, int tn, const void* A, const void* A2, const void* A3, int aBf16,
                   const float* B, void* C, int cBf16, const float* bias,
                   const float* addmat, int addCols, int addLd,
                   const float* lng, const float* lnb, float* rdOut,
                   int M, int N, int K, int lda, int ldb, int ldc){
    dim3 g(M / 64, N / tn, 1);
    if (tn == 128) {
      if (act == 0)      gemm_mfma_k<0,128><<<g, 256, 0, stream>>>(A, A2, A3, aBf16, B, C, cBf16, bias, addmat, addCols, addLd, lng, lnb, rdOut, M, N, K, lda, ldb, ldc);
      else if (act == 1) gemm_mfma_k<1,128><<<g, 256, 0, stream>>>(A, A2, A3, aBf16, B, C, cBf16, bias, addmat, addCols, addLd, lng, lnb, rdOut, M, N, K, lda, ldb, ldc);
      else               gemm_mfma_k<3,128><<<g, 256, 0, stream>>>(A, A2, A3, aBf16, B, C, cBf16, bias, addmat, addCols, addLd, lng, lnb, rdOut, M, N, K, lda, ldb, ldc);
    } else {
      if (act == 0)      gemm_mfma_k<0,64><<<g, 256, 0, stream>>>(A, A2, A3, aBf16, B, C, cBf16, bias, addmat, addCols, addLd, lng, lnb, rdOut, M, N, K, lda, ldb, ldc);
      else               gemm_mfma_k<1,64><<<g, 256, 0, stream>>>(A, A2, A3, aBf16, B, C, cBf16, bias, addmat, addCols, addLd, lng, lnb, rdOut, M, N, K, lda, ldb, ldc);
    }
  };

  // 1. zero-init (tiny)
  hipMemsetAsync(base + zstart, 0, zlen, stream);
  // 2. prep
  prep_k<<<4165, 256, 0, stream>>>(gat1_b, gat1_W, gt_Wq, gt_bq, gt_Wk, gt_bk, gt_Wv, gt_bv,
                                   peWQ, peWK, deg, gat1_as, gat1_ad, ap_dst, tp_dst, pa_dst,
                                   gt_Wo, gt_Wf1, gt_Wf2, cat_W, mlp_W1,
                                   bsum, Wqkv, bqkv, peW, Bstack, dbv, Ps, Pd, cnt,
                                   Wot, Wf1t, Wf2t, catt, mlp1t, Wqkvt);
  // 3. D1 mega-GEMM: 3 stage-0 MLPs + peQK (768 tiles)
  {
    GDescArr da; da.nd = 4;
    da.d[0] = { x_author, nullptr, t1_W, xa, t1_b, 0, 1, 1, NA, 128, 334, 334, 128, 128, 1, 0, 0, 0, 0 };
    da.d[1] = { x_paper,  nullptr, t2_W, xp, t2_b, 0, 1, 1, NPA, 128, 512, 512, 128, 128, 1, 0, 0, 0, 128 };
    da.d[2] = { x_term,   nullptr, t3_W, xt, t3_b, 0, 1, 1, NT, 128, 128, 128, 128, 128, 1, 0, 0, 0, 384 };
    da.d[3] = { pe_embed, nullptr, peW, peQK, nullptr, 0, 0, 0, NA, 256, 128, 128, 256, 256, 1, 0, 0, 0, 512 };
    gemm_multi_k<<<768, 256, 0, stream>>>(da);
  }
  // 4. CSR scan
  exscan_k<<<1, 1024, 0, stream>>>(cnt, offb, NSLOT);
  // 5. scorev + scatter co-dispatch
  score_scatter_k<<<SCV_BLOCKS + SCT_BLOCKS, 256, 0, stream>>>(xa, xp, xt, Ps, Pd, scores,
                                                               ap_dst, tp_dst, pa_dst,
                                                               offb, cur, eidx);
  // 6. GAT1 fused online softmax+aggregate
  agg8ff_k<<<NSLOT / 4, 256, 0, stream>>>(eidx, offb, cnt, ap_src, tp_src, pa_src,
                                          xa, xt, xp, scores, agg);
  // 7. D2 mega-GEMM + PE loss co-dispatch (3072 + 2048 blocks)
  {
    GDescArr da; da.nd = 2;
    da.d[0] = { agg, agg + (size_t)NPA * 1024, Bstack, accP, bsum, 1, 1, 1,
                NPA, 128, 256, 1024, 1024, 1024, 8, 128, 128, 128, 0 };
    da.d[1] = { agg + (size_t)2 * NPA * 1024, nullptr, gat1_W + 131072, accA, gat1_b + 1024, 1, 1, 1,
                NA, 128, 128, 1024, 1024, 1024, 8, 128, 128, 128, 2048 };
    d2loss_k<<<3072 + 2048, 256, 0, stream>>>(da, 3072, peQK, peQK + 128, original_A, lossAcc);
  }
  // 8-9. GAT2: hs2 GEMM + fused rowdot, then aggregation
  gemmx(3, 128, accP, 0, 0, 1, gat2_W + 131072, hs2, 1, 0, 0, 0, 0,
        gat2_as + 128, gat2_ad + 128, s2sd, NPA + NA, 128, 1024, 1024, 128, 128);
  gat_agg1f_k<<<NA / 4, 256, 0, stream>>>(eidx, offb + 2 * NPA, cnt + 2 * NPA, pa_src, hs2, s2sd,
                                          gat2_b + 128, hA2, NA);
  // 10. QKV layer 0
  gemmx(0, 64, hA2, 0, 0, 0, Wqkv, QKVb, 1, bqkv, peQK, 256, 256,
        0, 0, 0, NA, 384, 128, 128, 384, 384);
  // 11-12. attention + tail layer 0 (emits outs1 + QKVb for layer 1)
  attn_mfma_k<<<dim3(NA / 64, 8, ASPLIT), 256, 0, stream>>>(QKVb, QKVb + 128, QKVb + 256, dbv, part);
  gt_tail_k<0><<<NA / 16, 256, 0, stream>>>(part, Wot, gt_bo, hA2,
                                            gt_g1, gt_be1, Wf1t, gt_bf1, Wf2t, gt_bf2,
                                            gt_g2, gt_be2, outs1,
                                            Wqkvt + (size_t)49152, bqkv + 384, peQK, QKVb,
                                            nullptr, nullptr, nullptr, nullptr,
                                            nullptr, nullptr, nullptr, nullptr, nullptr, nullptr);
  // 13-14. attention + tail layer 1 (fused head)
  attn_mfma_k<<<dim3(NA / 64, 8, ASPLIT), 256, 0, stream>>>(QKVb, QKVb + 128, QKVb + 256, dbv, part);
  gt_tail_k<1><<<NA / 16, 256, 0, stream>>>(part, Wot + 16384, gt_bo + 128, outs1,
                                            gt_g1 + 128, gt_be1 + 128, Wf1t + 32768, gt_bf1 + 256,
                                            Wf2t + 32768, gt_bf2 + 128,
                                            gt_g2 + 128, gt_be2 + 128, nullptr,
                                            nullptr, nullptr, nullptr, nullptr,
                                            hA2, outs1, catt, cat_b, mlp1t, mlp_b1,
                                            mlp_W2, mlp_b2, lossAcc, out);
}